// Round 5
// baseline (246.397 us; speedup 1.0000x reference)
//
#include <hip/hip_runtime.h>
#include <stdint.h>

typedef unsigned short ushort_t;
typedef __bf16 bf16x8 __attribute__((ext_vector_type(8)));
typedef float floatx4 __attribute__((ext_vector_type(4)));

#define B_   8
#define S_   1024
#define D_   768
#define H_   12
#define M_   (B_ * S_)   // 8192
#define N3_  (3 * D_)    // 2304
#define QK_  1536        // qk buffer row stride (Q at +0, K at +768)

static __device__ __forceinline__ void gl_lds16(const void* g, void* l) {
  __builtin_amdgcn_global_load_lds((const __attribute__((address_space(1))) void*)g,
                                   (__attribute__((address_space(3))) void*)l,
                                   16, 0, 0);
}

static __device__ __forceinline__ ushort_t f2bf(float f) {
  __bf16 h = (__bf16)f;
  return __builtin_bit_cast(unsigned short, h);
}

static __device__ __forceinline__ void store_out(ushort_t* p, float v) { *p = f2bf(v); }
static __device__ __forceinline__ void store_out(float* p, float v) { *p = v; }

// ---------------------------------------------------------------------------
// Merged prep: x f32->bf16 (blocks 0..24575), w_qkv transpose (next 1728),
// w_proj transpose (next 576). (unchanged)
// ---------------------------------------------------------------------------
static __device__ __forceinline__ void transpose_tile(const float* __restrict__ W,
                                                      ushort_t* __restrict__ Wt,
                                                      int K, int N, int bx, int by,
                                                      int t) {
  __shared__ float tile[32][33];
  const int n0 = bx * 32, k0 = by * 32;
  const int tx = t & 31, ty = t >> 5;
#pragma unroll
  for (int i = 0; i < 4; ++i)
    tile[ty + i * 8][tx] = W[(size_t)(k0 + ty + i * 8) * N + n0 + tx];
  __syncthreads();
#pragma unroll
  for (int i = 0; i < 4; ++i)
    Wt[(size_t)(n0 + ty + i * 8) * K + k0 + tx] = f2bf(tile[tx][ty + i * 8]);
}

__global__ __launch_bounds__(256) void prep_kernel(const float* __restrict__ x,
                                                   ushort_t* __restrict__ xb,
                                                   const float* __restrict__ w_qkv,
                                                   ushort_t* __restrict__ wqkvt,
                                                   const float* __restrict__ w_proj,
                                                   ushort_t* __restrict__ wprojt) {
  const int gb = blockIdx.x, t = threadIdx.x;
  if (gb < 24576) {
    const int i = gb * 256 + t;
    xb[i] = f2bf(x[i]);
  } else if (gb < 24576 + 1728) {
    const int lb = gb - 24576;                 // 72 x 24 tiles
    transpose_tile(w_qkv, wqkvt, D_, N3_, lb % 72, lb / 72, t);
  } else {
    const int lb = gb - 24576 - 1728;          // 24 x 24 tiles
    transpose_tile(w_proj, wprojt, D_, D_, lb % 24, lb / 24, t);
  }
}

// ---------------------------------------------------------------------------
// GEMM 128x128, BK=32, 256 threads (4 waves, 2M x 2N), v5:
//   r4 post-mortem: GEMM is LDS-PIPE-bound (measured 1322 cyc/block-kt vs
//   ~800 cyc LDS demand incl. 4-way conflicts at ~2 blocks/CU). Fix = cut
//   LDS traffic 3x, not reshuffle it:
//   - B fragments load DIRECTLY global->VGPR (weights are L2-resident;
//     lane(l15,quad) reads Bt[n0+brow+ni*16][k0+quad*8], 16 rows x 64B =
//     fully-coalesced 16 lines/instr), 2-deep register pipeline prefetched
//     one K-tile ahead. Bs LDS buffer deleted.
//   - A stays in LDS (shared by 2 wn-waves), 2x8 KB double buffer.
//   - Swizzle bits CORRECTED: bank group of (row,slot) = 4*(row&1)+slot;
//     r4's slot=quad^(row&3) left only 2 slots per parity class -> 4-way.
//     Correct: slot = quad ^ ((row>>1)&3) -> every slot twice per parity ->
//     2-way = free (m136).
//   - one vmcnt(0)+s_barrier per K-tile (B loads had the full compute
//     window; A-dbuf WAR/RAW protected by the barrier).
//   - bijective XCD swizzle of linear blockIdx (grids 1152, 384: both %8==0)
// ---------------------------------------------------------------------------
template <typename OutT, bool SPLITV>
__global__ __launch_bounds__(256, 4) void gemm128(const ushort_t* __restrict__ A,
                                                  const ushort_t* __restrict__ Bt,
                                                  const float* __restrict__ bias,
                                                  OutT* __restrict__ C, int CN,
                                                  ushort_t* __restrict__ vt,
                                                  int NBX, int CHUNK) {
  __shared__ __align__(16) ushort_t As[2][128 * 32];   // 2 x 8 KB (A only)

  const int t = threadIdx.x;
  const int wave = t >> 6, lane = t & 63;
  const int quad = lane >> 4, l15 = lane & 15;
  const int wm = wave >> 1, wn = wave & 1;             // 2 x 2 wave grid

  // XCD-aware bijective swizzle (grid % 8 == 0 guaranteed by caller)
  const int g = blockIdx.x;
  const int swz = (g & 7) * CHUNK + (g >> 3);
  const int bx = swz % NBX, by = swz / NBX;
  const int m0 = by * 128, n0 = bx * 128;

  // A staging: thread covers row c*64 + wave*16 + (lane>>2), phys slot
  // lane&3. Stored logical granule l(r,s) = s ^ ((r>>1)&3); (rsub>>1)&3
  // == (lane>>3)&3 (wave*8, c*32 are 0 mod 4).
  const int rsub = wave * 16 + (lane >> 2);            // + c*64
  const int scol = ((lane & 3) ^ ((lane >> 3) & 3)) * 8;

  // A frag reads: row = wm*64 + mi*16 + l15 -> (row>>1)&3 == (l15>>1)&3
  const int slotq = (quad ^ ((l15 >> 1) & 3)) * 8;     // ushort offset in row

  const int arow = wm * 64 + l15;
  const int brow = wn * 64 + l15;

  const ushort_t* At  = A + (size_t)m0 * 768;
  const ushort_t* Bte = Bt + (size_t)n0 * 768;
  // per-lane B fragment base (row brow+ni*16, k-granule quad)
  const ushort_t* Bl  = Bte + (size_t)brow * 768 + quad * 8;

  floatx4 acc[4][4];
#pragma unroll
  for (int i = 0; i < 4; ++i)
#pragma unroll
    for (int j = 0; j < 4; ++j) acc[i][j] = (floatx4)0.0f;

  // prologue: B(0) -> b0 regs; stage A(0) into buf 0; drain; barrier
  bf16x8 b0[4], b1[4];
#pragma unroll
  for (int ni = 0; ni < 4; ++ni)
    b0[ni] = *(const bf16x8*)(Bl + (size_t)(ni * 16) * 768);
#pragma unroll
  for (int c = 0; c < 2; ++c)
    gl_lds16(At + (size_t)(c * 64 + rsub) * 768 + scol,
             &As[0][(c * 64 + wave * 16) * 32]);
  asm volatile("s_waitcnt vmcnt(0)" ::: "memory");
  __builtin_amdgcn_s_barrier();

  // K loop: 24 tiles, explicit 2-step unroll for static b0/b1 alternation
#pragma unroll 1
  for (int kt = 0; kt < 24; kt += 2) {
    // ---- step even: compute with b0, prefetch B(kt+1)->b1, A(kt+1)->buf^1
    {
      const ushort_t* Ab = As[0];
      if (kt + 1 < 24) {
        const int k1 = (kt + 1) * 32;
#pragma unroll
        for (int ni = 0; ni < 4; ++ni)
          b1[ni] = *(const bf16x8*)(Bl + (size_t)(ni * 16) * 768 + k1);
#pragma unroll
        for (int c = 0; c < 2; ++c)
          gl_lds16(At + (size_t)(c * 64 + rsub) * 768 + k1 + scol,
                   &As[1][(c * 64 + wave * 16) * 32]);
      }
      bf16x8 af[4];
#pragma unroll
      for (int mi = 0; mi < 4; ++mi)
        af[mi] = *(const bf16x8*)(Ab + (arow + mi * 16) * 32 + slotq);
#pragma unroll
      for (int mi = 0; mi < 4; ++mi)
#pragma unroll
        for (int ni = 0; ni < 4; ++ni)
          acc[mi][ni] = __builtin_amdgcn_mfma_f32_16x16x32_bf16(af[mi], b0[ni], acc[mi][ni], 0, 0, 0);
      asm volatile("s_waitcnt vmcnt(0)" ::: "memory");
      __builtin_amdgcn_s_barrier();
    }
    // ---- step odd: compute with b1, prefetch B(kt+2)->b0, A(kt+2)->buf 0
    {
      const ushort_t* Ab = As[1];
      if (kt + 2 < 24) {
        const int k2 = (kt + 2) * 32;
#pragma unroll
        for (int ni = 0; ni < 4; ++ni)
          b0[ni] = *(const bf16x8*)(Bl + (size_t)(ni * 16) * 768 + k2);
#pragma unroll
        for (int c = 0; c < 2; ++c)
          gl_lds16(At + (size_t)(c * 64 + rsub) * 768 + k2 + scol,
                   &As[0][(c * 64 + wave * 16) * 32]);
      }
      bf16x8 af[4];
#pragma unroll
      for (int mi = 0; mi < 4; ++mi)
        af[mi] = *(const bf16x8*)(Ab + (arow + mi * 16) * 32 + slotq);
#pragma unroll
      for (int mi = 0; mi < 4; ++mi)
#pragma unroll
        for (int ni = 0; ni < 4; ++ni)
          acc[mi][ni] = __builtin_amdgcn_mfma_f32_16x16x32_bf16(af[mi], b1[ni], acc[mi][ni], 0, 0, 0);
      asm volatile("s_waitcnt vmcnt(0)" ::: "memory");
      __builtin_amdgcn_s_barrier();
    }
  }

  // epilogue (verbatim from the r0/r3-verified kernel)
#pragma unroll
  for (int ni = 0; ni < 4; ++ni) {
    const int colb = n0 + wn * 64 + ni * 16;   // wave-uniform
    const int col = colb + l15;
    const float bb = bias[col];
    if (SPLITV && colb >= 1536) {
      const int hh = (colb - 1536) >> 6;
      const int d  = ((colb - 1536) & 63) + l15;
      const int bh = (m0 >> 10) * H_ + hh;
      ushort_t* vrow = vt + ((size_t)bh * 64 + d) * 1024 +
                       (m0 & 1023) + wm * 64 + quad * 4;
#pragma unroll
      for (int mi = 0; mi < 4; ++mi) {
        ushort4 pk;
        pk.x = f2bf(acc[mi][ni][0] + bb);
        pk.y = f2bf(acc[mi][ni][1] + bb);
        pk.z = f2bf(acc[mi][ni][2] + bb);
        pk.w = f2bf(acc[mi][ni][3] + bb);
        *(ushort4*)(vrow + mi * 16) = pk;
      }
    } else {
#pragma unroll
      for (int mi = 0; mi < 4; ++mi) {
#pragma unroll
        for (int r = 0; r < 4; ++r) {
          const int row = m0 + wm * 64 + mi * 16 + quad * 4 + r;
          store_out(&C[(size_t)row * CN + col], acc[mi][ni][r] + bb);
        }
      }
    }
  }
}

// ---------------------------------------------------------------------------
// Flash attention v4 (unchanged this round): 128 q-rows/block, 64-wide kv
// tiles, XOR-swizzled LDS, XCD-swizzled grid, fixed-max softmax.
// ---------------------------------------------------------------------------
__global__ __launch_bounds__(256) void attn_kernel(const ushort_t* __restrict__ qk,
                                                   const ushort_t* __restrict__ vt,
                                                   ushort_t* __restrict__ o) {
  __shared__ __align__(16) ushort_t Qs[128 * 64];   // 16 KB
  __shared__ __align__(16) ushort_t Ks[64 * 64];    //  8 KB
  __shared__ __align__(16) ushort_t Vts[64 * 64];   //  8 KB (V^T, swizzled)
  __shared__ __align__(16) ushort_t Ps[128 * 72];   // 18 KB

  const int t = threadIdx.x;
  const int wave = t >> 6, lane = t & 63;
  const int quad = lane >> 4, l15 = lane & 15;

  // XCD swizzle: 768 blocks; xcd=g&7 gets 12 contiguous bh, 8 q-tiles each.
  const int g = blockIdx.x;
  const int xcd = g & 7, gi = g >> 3;          // gi in 0..95
  const int bh = xcd * 12 + (gi >> 3);         // 0..95
  const int q0 = (gi & 7) * 128;
  const int h = bh % H_;
  const int bS = (bh / H_) * S_;
  const ushort_t* vbase = vt + (size_t)bh * 64 * 1024;

  // stage Q (once): 128x64 = 1024 granules of 16B, swizzled source
#pragma unroll
  for (int c = 0; c < 4; ++c) {
    const int i0 = c * 256 + wave * 64;  // wave-uniform
    const int i = i0 + lane;
    const int row = i >> 3, sg = (i & 7) ^ (row & 7);
    gl_lds16(qk + (size_t)(bS + q0 + row) * QK_ + h * 64 + sg * 8, Qs + i0 * 8);
  }
  __syncthreads();

  bf16x8 qf[2][2];
#pragma unroll
  for (int mi = 0; mi < 2; ++mi)
#pragma unroll
    for (int kb = 0; kb < 2; ++kb)
      qf[mi][kb] = *(const bf16x8*)(Qs + (wave * 32 + mi * 16 + l15) * 64 +
                                    (((kb * 4 + quad) ^ (l15 & 7)) * 8));

  floatx4 oa[2][4];
#pragma unroll
  for (int mi = 0; mi < 2; ++mi)
#pragma unroll
    for (int d = 0; d < 4; ++d) oa[mi][d] = (floatx4)0.0f;
  float lsum[2][4] = {{0.f, 0.f, 0.f, 0.f}, {0.f, 0.f, 0.f, 0.f}};

  for (int kv0 = 0; kv0 < S_; kv0 += 64) {
    // stage K and V^T tiles (512 granules each), swizzled source
#pragma unroll
    for (int c = 0; c < 2; ++c) {
      const int i0 = c * 256 + wave * 64;
      const int i = i0 + lane;
      const int row = i >> 3, sg = (i & 7) ^ (row & 7);
      gl_lds16(qk + (size_t)(bS + kv0 + row) * QK_ + 768 + h * 64 + sg * 8,
               Ks + i0 * 8);
      gl_lds16(vbase + (size_t)row * 1024 + kv0 + sg * 8, Vts + i0 * 8);
    }
    __syncthreads();

    // S = Q K^T : 2x4 blocks of 16x16, 16 MFMA
    floatx4 sa[2][4];
#pragma unroll
    for (int mi = 0; mi < 2; ++mi)
#pragma unroll
      for (int ni = 0; ni < 4; ++ni) sa[mi][ni] = (floatx4)0.0f;
#pragma unroll
    for (int ni = 0; ni < 4; ++ni)
#pragma unroll
      for (int kb = 0; kb < 2; ++kb) {
        const bf16x8 kf = *(const bf16x8*)(Ks + (ni * 16 + l15) * 64 +
                                           (((kb * 4 + quad) ^ (l15 & 7)) * 8));
#pragma unroll
        for (int mi = 0; mi < 2; ++mi)
          sa[mi][ni] = __builtin_amdgcn_mfma_f32_16x16x32_bf16(qf[mi][kb], kf, sa[mi][ni], 0, 0, 0);
      }

    // fixed-max softmax: p = exp(s*0.125 - 16); lane-local l accumulation
#pragma unroll
    for (int mi = 0; mi < 2; ++mi)
#pragma unroll
      for (int r = 0; r < 4; ++r) {
        float psum = 0.0f;
#pragma unroll
        for (int ni = 0; ni < 4; ++ni) {
          const float p = __expf(fmaf(sa[mi][ni][r], 0.125f, -16.0f));
          psum += p;
          Ps[(wave * 32 + mi * 16 + quad * 4 + r) * 72 + ni * 16 + l15] = f2bf(p);
        }
        lsum[mi][r] += psum;
      }
    // Ps rows [wave*32, wave*32+32) are wave-private; lgkmcnt orders wr->rd.

    // O += P V : 16 MFMA
#pragma unroll
    for (int kb = 0; kb < 2; ++kb) {
      bf16x8 vf[4];
#pragma unroll
      for (int dt = 0; dt < 4; ++dt)
        vf[dt] = *(const bf16x8*)(Vts + (dt * 16 + l15) * 64 +
                                  (((kb * 4 + quad) ^ (l15 & 7)) * 8));
#pragma unroll
      for (int mi = 0; mi < 2; ++mi) {
        const bf16x8 pf = *(const bf16x8*)(Ps + (wave * 32 + mi * 16 + l15) * 72 +
                                           kb * 32 + quad * 8);
#pragma unroll
        for (int dt = 0; dt < 4; ++dt)
          oa[mi][dt] = __builtin_amdgcn_mfma_f32_16x16x32_bf16(pf, vf[dt], oa[mi][dt], 0, 0, 0);
      }
    }
    __syncthreads();
  }

  // one-time l reduction across the 16-lane row groups
#pragma unroll
  for (int mi = 0; mi < 2; ++mi)
#pragma unroll
    for (int r = 0; r < 4; ++r) {
#pragma unroll
      for (int off = 8; off >= 1; off >>= 1)
        lsum[mi][r] += __shfl_xor(lsum[mi][r], off, 64);
    }

  // epilogue: normalize and store [B,S,H*Hd] bf16
#pragma unroll
  for (int mi = 0; mi < 2; ++mi)
#pragma unroll
    for (int dt = 0; dt < 4; ++dt)
#pragma unroll
      for (int r = 0; r < 4; ++r) {
        const int q = q0 + wave * 32 + mi * 16 + quad * 4 + r;
        o[(size_t)(bS + q) * D_ + h * 64 + dt * 16 + l15] =
            f2bf(oa[mi][dt][r] / lsum[mi][r]);
      }
}

// ---------------------------------------------------------------------------
extern "C" void kernel_launch(void* const* d_in, const int* in_sizes, int n_in,
                              void* d_out, int out_size, void* d_ws, size_t ws_size,
                              hipStream_t stream) {
  const float* x      = (const float*)d_in[0];  // [8192, 768] f32
  const float* w_qkv  = (const float*)d_in[1];  // [768, 2304] f32
  const float* b_qkv  = (const float*)d_in[2];  // [2304] f32
  const float* w_proj = (const float*)d_in[3];  // [768, 768] f32
  const float* b_proj = (const float*)d_in[4];  // [768] f32
  float* out = (float*)d_out;                   // [8192, 768] f32

  ushort_t* xb = (ushort_t*)d_out;  // x as bf16, dead before proj GEMM writes

  // ws layout (bf16 units), 55.05 MB total (fault-free footprint r3-r9)
  ushort_t* vtb    = (ushort_t*)d_ws;              // [96*64, 1024] 12.58 MB
  ushort_t* wqkvt  = vtb + (size_t)96 * 64 * 1024; // [2304, 768]    3.54 MB
  ushort_t* wprojt = wqkvt + (size_t)N3_ * D_;     // [768, 768]     1.18 MB
  ushort_t* qkb    = wprojt + (size_t)D_ * D_;     // [8192, 1536]  25.17 MB
  ushort_t* attnb  = qkb + (size_t)M_ * QK_;       // [8192, 768]   12.58 MB

  prep_kernel<<<24576 + 1728 + 576, 256, 0, stream>>>(x, xb, w_qkv, wqkvt,
                                                      w_proj, wprojt);
  // QKV: M=8192, N=2304 -> 64 x 18 = 1152 blocks (1152 = 8*144)
  gemm128<ushort_t, true><<<1152, 256, 0, stream>>>(xb, wqkvt, b_qkv, qkb, QK_,
                                                    vtb, 18, 144);
  attn_kernel<<<dim3(768), 256, 0, stream>>>(qkb, vtb, attnb);
  // proj: M=8192, N=768 -> 64 x 6 = 384 blocks (384 = 8*48)
  gemm128<float, false><<<384, 256, 0, stream>>>(attnb, wprojt, b_proj, out, D_,
                                                 nullptr, 6, 48);
}

// Round 6
// 200.598 us; speedup vs baseline: 1.2283x; 1.2283x over previous
//
#include <hip/hip_runtime.h>
#include <stdint.h>

typedef unsigned short ushort_t;
typedef __bf16 bf16x8 __attribute__((ext_vector_type(8)));
typedef float floatx4 __attribute__((ext_vector_type(4)));

#define B_   8
#define S_   1024
#define D_   768
#define H_   12
#define M_   (B_ * S_)   // 8192
#define N3_  (3 * D_)    // 2304
#define QK_  1536        // qk buffer row stride (Q at +0, K at +768)

static __device__ __forceinline__ void gl_lds16(const void* g, void* l) {
  __builtin_amdgcn_global_load_lds((const __attribute__((address_space(1))) void*)g,
                                   (__attribute__((address_space(3))) void*)l,
                                   16, 0, 0);
}

static __device__ __forceinline__ ushort_t f2bf(float f) {
  __bf16 h = (__bf16)f;
  return __builtin_bit_cast(unsigned short, h);
}

static __device__ __forceinline__ void store_out(ushort_t* p, float v) { *p = f2bf(v); }
static __device__ __forceinline__ void store_out(float* p, float v) { *p = v; }

// ---------------------------------------------------------------------------
// prep: weight transposes only (x-conversion now fused into the QKV GEMM).
// blocks 0..1727: w_qkv (72x24 tiles); 1728..2303: w_proj (24x24 tiles).
// ---------------------------------------------------------------------------
static __device__ __forceinline__ void transpose_tile(const float* __restrict__ W,
                                                      ushort_t* __restrict__ Wt,
                                                      int K, int N, int bx, int by,
                                                      int t) {
  __shared__ float tile[32][33];
  const int n0 = bx * 32, k0 = by * 32;
  const int tx = t & 31, ty = t >> 5;
#pragma unroll
  for (int i = 0; i < 4; ++i)
    tile[ty + i * 8][tx] = W[(size_t)(k0 + ty + i * 8) * N + n0 + tx];
  __syncthreads();
#pragma unroll
  for (int i = 0; i < 4; ++i)
    Wt[(size_t)(n0 + ty + i * 8) * K + k0 + tx] = f2bf(tile[tx][ty + i * 8]);
}

__global__ __launch_bounds__(256) void prep_kernel(const float* __restrict__ w_qkv,
                                                   ushort_t* __restrict__ wqkvt,
                                                   const float* __restrict__ w_proj,
                                                   ushort_t* __restrict__ wprojt) {
  const int gb = blockIdx.x, t = threadIdx.x;
  if (gb < 1728) {
    transpose_tile(w_qkv, wqkvt, D_, N3_, gb % 72, gb / 72, t);
  } else {
    const int lb = gb - 1728;                  // 24 x 24 tiles
    transpose_tile(w_proj, wprojt, D_, D_, lb % 24, lb / 24, t);
  }
}

// ---------------------------------------------------------------------------
// GEMM 128x128, BK=32, 256 threads (4 waves, 2M x 2N), v6:
//   r5 post-mortem: B-to-VGPR scattered loads = disaster (93us); every
//   gl_lds-based schedule lands 57-62us. This round removes WORK:
//   - AF32: A staged directly from f32 x by REG-staging (2x float4 load ->
//     cvt -> swizzled ds_write_b128). Kills the 24576-block prep x-pass and
//     the xb HBM roundtrip. Reg-staging writes the swizzle on the LDS addr.
//   - corrected XOR swizzle everywhere (verified r5: 0 conflicts):
//     stored logical granule = slot ^ ((row>>1)&3); staging source/write
//     uses (lane&3)^((lane>>3)&3); frag reads use quad^((l15>>1)&3).
//   - r4 pipelined double-buffer schedule: issue loads(kt+1) at top,
//     compute(kt), cvt+ds_write(kt+1) at tail, __syncthreads per step
//     (its vmcnt(0)+lgkmcnt(0) drain IS the intended sync).
//   - bijective XCD swizzle of linear blockIdx (grids 1152, 384: both %8==0)
// ---------------------------------------------------------------------------
template <typename OutT, bool SPLITV, bool AF32>
__global__ __launch_bounds__(256, 4) void gemm128(const void* __restrict__ Ap,
                                                  const ushort_t* __restrict__ Bt,
                                                  const float* __restrict__ bias,
                                                  OutT* __restrict__ C, int CN,
                                                  ushort_t* __restrict__ vt,
                                                  int NBX, int CHUNK) {
  __shared__ __align__(16) ushort_t As[2][128 * 32];   // 2 x 8 KB
  __shared__ __align__(16) ushort_t Bs[2][128 * 32];   // 2 x 8 KB

  const int t = threadIdx.x;
  const int wave = t >> 6, lane = t & 63;
  const int quad = lane >> 4, l15 = lane & 15;
  const int wm = wave >> 1, wn = wave & 1;             // 2 x 2 wave grid

  // XCD-aware bijective swizzle (grid % 8 == 0 guaranteed by caller)
  const int g = blockIdx.x;
  const int swz = (g & 7) * CHUNK + (g >> 3);
  const int bx = swz % NBX, by = swz / NBX;
  const int m0 = by * 128, n0 = bx * 128;

  // gl_lds staging (B always; A when !AF32): thread covers row
  // c*64 + wave*16 + (lane>>2), phys slot lane&3; source granule
  // (lane&3)^((lane>>3)&3)  [== slot ^ ((row>>1)&3), r5-verified 0-conflict]
  const int rsub = wave * 16 + (lane >> 2);            // + c*64
  const int scol = ((lane & 3) ^ ((lane >> 3) & 3)) * 8;

  // frag reads: row = base+l15 (base mult of 16) -> (row>>1)&3 == (l15>>1)&3
  const int slotq = (quad ^ ((l15 >> 1) & 3)) * 8;     // ushort offset in row

  const int arow = wm * 64 + l15;
  const int brow = wn * 64 + l15;

  const float*    Ax  = (const float*)Ap + (size_t)m0 * 768;     // AF32
  const ushort_t* At  = (const ushort_t*)Ap + (size_t)m0 * 768;  // !AF32
  const ushort_t* Bte = Bt + (size_t)n0 * 768;

  // reg-staging constants (AF32): granule gidx = it*256 + t
  // row = it*64 + wave*16 + (lane>>2), slot = lane&3, lg = scol (same bits)
  const int xrow0 = wave * 16 + (lane >> 2);           // + it*64
  const int xslot = (lane & 3) * 8;                    // phys slot (ushorts)

  floatx4 acc[4][4];
#pragma unroll
  for (int i = 0; i < 4; ++i)
#pragma unroll
    for (int j = 0; j < 4; ++j) acc[i][j] = (floatx4)0.0f;

  // ---- prologue: stage K-tile 0 into buffer 0
  if (AF32) {
    floatx4 xa[2][2];
#pragma unroll
    for (int it = 0; it < 2; ++it) {
      const float* src = Ax + (size_t)(it * 64 + xrow0) * 768 + scol;
      xa[it][0] = *(const floatx4*)(src);
      xa[it][1] = *(const floatx4*)(src + 4);
    }
#pragma unroll
    for (int c = 0; c < 2; ++c)
      gl_lds16(Bte + (size_t)(c * 64 + rsub) * 768 + scol,
               &Bs[0][(c * 64 + wave * 16) * 32]);
#pragma unroll
    for (int it = 0; it < 2; ++it) {
      bf16x8 w;
#pragma unroll
      for (int j = 0; j < 4; ++j) {
        w[j]     = (__bf16)xa[it][0][j];
        w[4 + j] = (__bf16)xa[it][1][j];
      }
      *(bf16x8*)(&As[0][(it * 64 + xrow0) * 32 + xslot]) = w;
    }
  } else {
#pragma unroll
    for (int c = 0; c < 2; ++c) {
      gl_lds16(At + (size_t)(c * 64 + rsub) * 768 + scol,
               &As[0][(c * 64 + wave * 16) * 32]);
      gl_lds16(Bte + (size_t)(c * 64 + rsub) * 768 + scol,
               &Bs[0][(c * 64 + wave * 16) * 32]);
    }
  }
  __syncthreads();

#pragma unroll 2
  for (int kt = 0; kt < 24; ++kt) {
    const ushort_t* Ab = As[kt & 1];
    const ushort_t* Bb = Bs[kt & 1];
    const bool p1 = (kt + 1) < 24;
    const int k1 = (kt + 1) * 32;
    ushort_t* An = As[(kt + 1) & 1];
    ushort_t* Bn = Bs[(kt + 1) & 1];

    // issue next tile's loads FIRST (land during compute below)
    floatx4 xa[2][2];
    if (p1) {
      if (AF32) {
#pragma unroll
        for (int it = 0; it < 2; ++it) {
          const float* src = Ax + (size_t)(it * 64 + xrow0) * 768 + k1 + scol;
          xa[it][0] = *(const floatx4*)(src);
          xa[it][1] = *(const floatx4*)(src + 4);
        }
      } else {
#pragma unroll
        for (int c = 0; c < 2; ++c)
          gl_lds16(At + (size_t)(c * 64 + rsub) * 768 + k1 + scol,
                   An + (c * 64 + wave * 16) * 32);
      }
#pragma unroll
      for (int c = 0; c < 2; ++c)
        gl_lds16(Bte + (size_t)(c * 64 + rsub) * 768 + k1 + scol,
                 Bn + (c * 64 + wave * 16) * 32);
    }

    // compute current tile: 8 ds_read_b128 + 16 MFMA per wave
    bf16x8 af[4], bfr[4];
#pragma unroll
    for (int mi = 0; mi < 4; ++mi)
      af[mi] = *(const bf16x8*)(Ab + (arow + mi * 16) * 32 + slotq);
#pragma unroll
    for (int ni = 0; ni < 4; ++ni)
      bfr[ni] = *(const bf16x8*)(Bb + (brow + ni * 16) * 32 + slotq);
#pragma unroll
    for (int mi = 0; mi < 4; ++mi)
#pragma unroll
      for (int ni = 0; ni < 4; ++ni)
        acc[mi][ni] = __builtin_amdgcn_mfma_f32_16x16x32_bf16(af[mi], bfr[ni], acc[mi][ni], 0, 0, 0);

    // tail: AF32 converts+writes the prefetched A (compiler inserts the
    // precise vmcnt before first use of xa)
    if (AF32 && p1) {
#pragma unroll
      for (int it = 0; it < 2; ++it) {
        bf16x8 w;
#pragma unroll
        for (int j = 0; j < 4; ++j) {
          w[j]     = (__bf16)xa[it][0][j];
          w[4 + j] = (__bf16)xa[it][1][j];
        }
        *(bf16x8*)(&An[(it * 64 + xrow0) * 32 + xslot]) = w;
      }
    }
    __syncthreads();   // drains gl_lds (vmcnt) + orders ds_write (lgkmcnt)
  }

  // epilogue (verbatim from the r0-verified kernel)
#pragma unroll
  for (int ni = 0; ni < 4; ++ni) {
    const int colb = n0 + wn * 64 + ni * 16;   // wave-uniform
    const int col = colb + l15;
    const float bb = bias[col];
    if (SPLITV && colb >= 1536) {
      const int hh = (colb - 1536) >> 6;
      const int d  = ((colb - 1536) & 63) + l15;
      const int bh = (m0 >> 10) * H_ + hh;
      ushort_t* vrow = vt + ((size_t)bh * 64 + d) * 1024 +
                       (m0 & 1023) + wm * 64 + quad * 4;
#pragma unroll
      for (int mi = 0; mi < 4; ++mi) {
        ushort4 pk;
        pk.x = f2bf(acc[mi][ni][0] + bb);
        pk.y = f2bf(acc[mi][ni][1] + bb);
        pk.z = f2bf(acc[mi][ni][2] + bb);
        pk.w = f2bf(acc[mi][ni][3] + bb);
        *(ushort4*)(vrow + mi * 16) = pk;
      }
    } else {
#pragma unroll
      for (int mi = 0; mi < 4; ++mi) {
#pragma unroll
        for (int r = 0; r < 4; ++r) {
          const int row = m0 + wm * 64 + mi * 16 + quad * 4 + r;
          store_out(&C[(size_t)row * CN + col], acc[mi][ni][r] + bb);
        }
      }
    }
  }
}

// ---------------------------------------------------------------------------
// Flash attention v4 (unchanged this round): 128 q-rows/block, 64-wide kv
// tiles, XOR-swizzled LDS, XCD-swizzled grid, fixed-max softmax.
// ---------------------------------------------------------------------------
__global__ __launch_bounds__(256) void attn_kernel(const ushort_t* __restrict__ qk,
                                                   const ushort_t* __restrict__ vt,
                                                   ushort_t* __restrict__ o) {
  __shared__ __align__(16) ushort_t Qs[128 * 64];   // 16 KB
  __shared__ __align__(16) ushort_t Ks[64 * 64];    //  8 KB
  __shared__ __align__(16) ushort_t Vts[64 * 64];   //  8 KB (V^T, swizzled)
  __shared__ __align__(16) ushort_t Ps[128 * 72];   // 18 KB

  const int t = threadIdx.x;
  const int wave = t >> 6, lane = t & 63;
  const int quad = lane >> 4, l15 = lane & 15;

  // XCD swizzle: 768 blocks; xcd=g&7 gets 12 contiguous bh, 8 q-tiles each.
  const int g = blockIdx.x;
  const int xcd = g & 7, gi = g >> 3;          // gi in 0..95
  const int bh = xcd * 12 + (gi >> 3);         // 0..95
  const int q0 = (gi & 7) * 128;
  const int h = bh % H_;
  const int bS = (bh / H_) * S_;
  const ushort_t* vbase = vt + (size_t)bh * 64 * 1024;

  // stage Q (once): 128x64 = 1024 granules of 16B, swizzled source
#pragma unroll
  for (int c = 0; c < 4; ++c) {
    const int i0 = c * 256 + wave * 64;  // wave-uniform
    const int i = i0 + lane;
    const int row = i >> 3, sg = (i & 7) ^ (row & 7);
    gl_lds16(qk + (size_t)(bS + q0 + row) * QK_ + h * 64 + sg * 8, Qs + i0 * 8);
  }
  __syncthreads();

  bf16x8 qf[2][2];
#pragma unroll
  for (int mi = 0; mi < 2; ++mi)
#pragma unroll
    for (int kb = 0; kb < 2; ++kb)
      qf[mi][kb] = *(const bf16x8*)(Qs + (wave * 32 + mi * 16 + l15) * 64 +
                                    (((kb * 4 + quad) ^ (l15 & 7)) * 8));

  floatx4 oa[2][4];
#pragma unroll
  for (int mi = 0; mi < 2; ++mi)
#pragma unroll
    for (int d = 0; d < 4; ++d) oa[mi][d] = (floatx4)0.0f;
  float lsum[2][4] = {{0.f, 0.f, 0.f, 0.f}, {0.f, 0.f, 0.f, 0.f}};

  for (int kv0 = 0; kv0 < S_; kv0 += 64) {
    // stage K and V^T tiles (512 granules each), swizzled source
#pragma unroll
    for (int c = 0; c < 2; ++c) {
      const int i0 = c * 256 + wave * 64;
      const int i = i0 + lane;
      const int row = i >> 3, sg = (i & 7) ^ (row & 7);
      gl_lds16(qk + (size_t)(bS + kv0 + row) * QK_ + 768 + h * 64 + sg * 8,
               Ks + i0 * 8);
      gl_lds16(vbase + (size_t)row * 1024 + kv0 + sg * 8, Vts + i0 * 8);
    }
    __syncthreads();

    // S = Q K^T : 2x4 blocks of 16x16, 16 MFMA
    floatx4 sa[2][4];
#pragma unroll
    for (int mi = 0; mi < 2; ++mi)
#pragma unroll
      for (int ni = 0; ni < 4; ++ni) sa[mi][ni] = (floatx4)0.0f;
#pragma unroll
    for (int ni = 0; ni < 4; ++ni)
#pragma unroll
      for (int kb = 0; kb < 2; ++kb) {
        const bf16x8 kf = *(const bf16x8*)(Ks + (ni * 16 + l15) * 64 +
                                           (((kb * 4 + quad) ^ (l15 & 7)) * 8));
#pragma unroll
        for (int mi = 0; mi < 2; ++mi)
          sa[mi][ni] = __builtin_amdgcn_mfma_f32_16x16x32_bf16(qf[mi][kb], kf, sa[mi][ni], 0, 0, 0);
      }

    // fixed-max softmax: p = exp(s*0.125 - 16); lane-local l accumulation
#pragma unroll
    for (int mi = 0; mi < 2; ++mi)
#pragma unroll
      for (int r = 0; r < 4; ++r) {
        float psum = 0.0f;
#pragma unroll
        for (int ni = 0; ni < 4; ++ni) {
          const float p = __expf(fmaf(sa[mi][ni][r], 0.125f, -16.0f));
          psum += p;
          Ps[(wave * 32 + mi * 16 + quad * 4 + r) * 72 + ni * 16 + l15] = f2bf(p);
        }
        lsum[mi][r] += psum;
      }
    // Ps rows [wave*32, wave*32+32) are wave-private; lgkmcnt orders wr->rd.

    // O += P V : 16 MFMA
#pragma unroll
    for (int kb = 0; kb < 2; ++kb) {
      bf16x8 vf[4];
#pragma unroll
      for (int dt = 0; dt < 4; ++dt)
        vf[dt] = *(const bf16x8*)(Vts + (dt * 16 + l15) * 64 +
                                  (((kb * 4 + quad) ^ (l15 & 7)) * 8));
#pragma unroll
      for (int mi = 0; mi < 2; ++mi) {
        const bf16x8 pf = *(const bf16x8*)(Ps + (wave * 32 + mi * 16 + l15) * 72 +
                                           kb * 32 + quad * 8);
#pragma unroll
        for (int dt = 0; dt < 4; ++dt)
          oa[mi][dt] = __builtin_amdgcn_mfma_f32_16x16x32_bf16(pf, vf[dt], oa[mi][dt], 0, 0, 0);
      }
    }
    __syncthreads();
  }

  // one-time l reduction across the 16-lane row groups
#pragma unroll
  for (int mi = 0; mi < 2; ++mi)
#pragma unroll
    for (int r = 0; r < 4; ++r) {
#pragma unroll
      for (int off = 8; off >= 1; off >>= 1)
        lsum[mi][r] += __shfl_xor(lsum[mi][r], off, 64);
    }

  // epilogue: normalize and store [B,S,H*Hd] bf16
#pragma unroll
  for (int mi = 0; mi < 2; ++mi)
#pragma unroll
    for (int dt = 0; dt < 4; ++dt)
#pragma unroll
      for (int r = 0; r < 4; ++r) {
        const int q = q0 + wave * 32 + mi * 16 + quad * 4 + r;
        o[(size_t)(bS + q) * D_ + h * 64 + dt * 16 + l15] =
            f2bf(oa[mi][dt][r] / lsum[mi][r]);
      }
}

// ---------------------------------------------------------------------------
extern "C" void kernel_launch(void* const* d_in, const int* in_sizes, int n_in,
                              void* d_out, int out_size, void* d_ws, size_t ws_size,
                              hipStream_t stream) {
  const float* x      = (const float*)d_in[0];  // [8192, 768] f32
  const float* w_qkv  = (const float*)d_in[1];  // [768, 2304] f32
  const float* b_qkv  = (const float*)d_in[2];  // [2304] f32
  const float* w_proj = (const float*)d_in[3];  // [768, 768] f32
  const float* b_proj = (const float*)d_in[4];  // [768] f32
  float* out = (float*)d_out;                   // [8192, 768] f32

  // ws layout (bf16 units); xb eliminated (x staged f32->bf16 inside QKV)
  ushort_t* vtb    = (ushort_t*)d_ws;              // [96*64, 1024] 12.58 MB
  ushort_t* wqkvt  = vtb + (size_t)96 * 64 * 1024; // [2304, 768]    3.54 MB
  ushort_t* wprojt = wqkvt + (size_t)N3_ * D_;     // [768, 768]     1.18 MB
  ushort_t* qkb    = wprojt + (size_t)D_ * D_;     // [8192, 1536]  25.17 MB
  ushort_t* attnb  = qkb + (size_t)M_ * QK_;       // [8192, 768]   12.58 MB

  prep_kernel<<<1728 + 576, 256, 0, stream>>>(w_qkv, wqkvt, w_proj, wprojt);
  // QKV: M=8192, N=2304 -> 64 x 18 = 1152 blocks (1152 = 8*144); A = f32 x
  gemm128<ushort_t, true, true><<<1152, 256, 0, stream>>>(x, wqkvt, b_qkv, qkb,
                                                          QK_, vtb, 18, 144);
  attn_kernel<<<dim3(768), 256, 0, stream>>>(qkb, vtb, attnb);
  // proj: M=8192, N=768 -> 64 x 6 = 384 blocks (384 = 8*48); A = bf16 attnb
  gemm128<float, false, false><<<384, 256, 0, stream>>>(attnb, wprojt, b_proj,
                                                        out, D_, nullptr, 6, 48);
}